// Round 10
// baseline (548.636 us; speedup 1.0000x reference)
//
#include <hip/hip_runtime.h>
#include <hip/hip_bf16.h>
#include <hip/hip_cooperative_groups.h>
namespace cg = cooperative_groups;

#define NCh 256   // scan chunks
#define CLh 32    // chunk length
#define LOG2E 1.44269504088896f

typedef short bf16x8 __attribute__((ext_vector_type(8)));
typedef float f32x4 __attribute__((ext_vector_type(4)));

static __device__ __forceinline__ float nexp2(float x) {
#if __has_builtin(__builtin_amdgcn_exp2f)
    return __builtin_amdgcn_exp2f(x);
#else
    return exp2f(x);
#endif
}
static __device__ __forceinline__ float sigm(float x) {
    return 1.f / (1.f + nexp2(-x * LOG2E));
}
static __device__ __forceinline__ ushort f2bf(float x) {
    union { float f; uint u; } v; v.f = x;
    uint r = v.u + 0x7fffu + ((v.u >> 16) & 1u);
    return (ushort)(r >> 16);
}
static __device__ __forceinline__ float bf2f(ushort h) {
    union { float f; uint u; } v; v.u = ((uint)h) << 16;
    return v.f;
}
static __device__ __forceinline__ void f2hl(float x, ushort* hi, ushort* lo) {
    ushort h = f2bf(x);
    *hi = h;
    *lo = f2bf(x - bf2f(h));
}

// weight regions in wH/wL (ushort elems), K-major [n][k]
#define W_PE   0
#define W_WIN  16384
#define W_WOUT 81920
#define W_PU   114688
#define W_PROJ 131072
#define W_TOT  212992

struct KParams {
    const float *ks, *mask, *pe_w, *pe_b, *pu_w, *pu_b, *ln_g, *ln_b, *fn_g, *fn_b;
    const float *cond_band, *cond_rad, *cond_mask, *Win, *bin_, *convw, *convb, *Wx, *Wdt, *bdt;
    const float *Alog, *Dp, *Wout, *bout, *edt, *eB, *eC, *wr, *wm;
    ushort *wH, *wL;
    float *mbuf, *h_;
    ushort *hnH, *hnL;
    float *xp, *sz, *xc, *dt, *Bm, *Cm, *Hb, *Hpre, *sdtb;
    ushort *AHo, *ALo, *hfH, *hfL;
    float *out;
};

// scan core with compile-time direction (dynamic yreg index => scratch spill; DIR template keeps it in VGPRs)
template <int DIR>
static __device__ __forceinline__ void scan_dir(const float* __restrict__ dt, const float* __restrict__ xc,
                                                int base, int e,
                                                const float (*bms)[16], const float (*cms)[16],
                                                const float* A2, const float* iv,
                                                float* h, float* yreg) {
    float cu[8], cx[8], nu[8], nx[8];
#pragma unroll
    for (int j = 0; j < 8; ++j) {
        const int p = DIR ? (CLh - 1 - j) : j;
        cu[j] = dt[(size_t)(base + p) * 256 + e];
        cx[j] = xc[(size_t)(base + p) * 256 + e];
    }
#pragma unroll
    for (int g = 0; g < CLh / 8; ++g) {
        if (g + 1 < CLh / 8) {
#pragma unroll
            for (int j = 0; j < 8; ++j) {
                const int s = (g + 1) * 8 + j;
                const int p = DIR ? (CLh - 1 - s) : s;
                nu[j] = dt[(size_t)(base + p) * 256 + e];
                nx[j] = xc[(size_t)(base + p) * 256 + e];
            }
        }
#pragma unroll
        for (int j = 0; j < 8; ++j) {
            const int s = g * 8 + j;
            const int p = DIR ? (CLh - 1 - s) : s;
            float u = cu[j], xv = cx[j];
            union { float4 v[4]; float f[16]; } bb, cc;
            const float4* bp = (const float4*)&bms[p][0];
            bb.v[0] = bp[0]; bb.v[1] = bp[1]; bb.v[2] = bp[2]; bb.v[3] = bp[3];
            const float4* cp = (const float4*)&cms[p][0];
            cc.v[0] = cp[0]; cc.v[1] = cp[1]; cc.v[2] = cp[2]; cc.v[3] = cp[3];
            float y = 0.f;
#pragma unroll
            for (int n = 0; n < 16; ++n) {
                float a = nexp2(A2[n] * u);
                float w = xv * bb.f[n] * iv[n];
                h[n] = a * (h[n] + w) - w;
                y += h[n] * cc.f[n];
            }
            yreg[p] = y;
        }
#pragma unroll
        for (int j = 0; j < 8; ++j) { cu[j] = nu[j]; cx[j] = nx[j]; }
    }
}

__global__ __launch_bounds__(512) void mega_k(KParams P) {
    cg::grid_group gg = cg::this_grid();
    __shared__ __align__(16) char smem[55296];
    const int tid = threadIdx.x;
    const int b = blockIdx.x;
    const int gtid = b * 512 + tid;

    // ================= P0: weight prep (+ Wx@Wdt fuse) + maskpool =================
    for (int i = gtid; i < 221184; i += 131072) {
        if (i < 212992) {
            float v;
            if (i < 16384) {
                v = P.pe_w[i];
            } else if (i < 81920) {
                int j = i - 16384; int n = j >> 7, k = j & 127;
                v = P.Win[k * 512 + n];
            } else if (i < 114688) {
                int j = i - 81920; int n = j >> 8, k = j & 255;
                v = P.Wout[k * 128 + n];
            } else if (i < 131072) {
                int j = i - 114688; int n = j >> 7, k = j & 127;
                v = P.pu_w[k * 128 + n];
            } else {
                int j = i - 131072; int n = j >> 8, k = j & 255;
                if (n < 256) {
                    float s = 0.f;
#pragma unroll
                    for (int r = 0; r < 8; ++r) s += P.Wx[k * 40 + r] * P.Wdt[r * 256 + n];
                    v = s;
                } else if (n < 288) {
                    v = P.Wx[k * 40 + 8 + (n - 256)];
                } else {
                    v = 0.f;
                }
            }
            ushort hh, ll; f2hl(v, &hh, &ll);
            P.wH[i] = hh; P.wL[i] = ll;
        } else {
            int l = i - 212992;
            int xg = l >> 8, yg = (l >> 3) & 31, zg = l & 7;
            float s = 0.f;
            for (int i2 = 0; i2 < 2; ++i2)
                for (int j2 = 0; j2 < 2; ++j2)
                    for (int k2 = 0; k2 < 2; ++k2)
                        s += P.mask[(2 * xg + i2) * 1024 + (2 * yg + j2) * 16 + 2 * zg + k2];
            P.mbuf[l] = fminf(fmaxf(s * 0.125f, 0.f), 1.f);
        }
    }
    gg.sync();

    // ================= P1: gather -> embed GEMM (+cond) -> LN2 -> h_, hn =========
    {
        ushort (*AsH)[72] = (ushort(*)[72])(smem);
        ushort (*AsL)[72] = (ushort(*)[72])(smem + 4608);
        ushort (*BsH)[72] = (ushort(*)[72])(smem + 9216);
        ushort (*BsL)[72] = (ushort(*)[72])(smem + 27648);
        float  (*Cs)[132] = (float(*)[132])(smem);
        const int lane = tid & 63, wv = tid >> 6;
        const int ln = lane & 15, q = lane >> 4;
        const int mb = b * 32;
        f32x4 acc[2];
        acc[0] = (f32x4){0.f, 0.f, 0.f, 0.f};
        acc[1] = (f32x4){0.f, 0.f, 0.f, 0.f};
        for (int kc = 0; kc < 128; kc += 64) {
            __syncthreads();
            for (int u = tid; u < 2048; u += 512) {
                int r = u >> 6, kk = u & 63;
                int l = mb + r, k = kc + kk;
                int cc = k >> 3, ijk = k & 7;
                int xg = l >> 8, yg = (l >> 3) & 31, zg = l & 7;
                int i2 = (ijk >> 2) & 1, j2 = (ijk >> 1) & 1, k2 = ijk & 1;
                float v = P.ks[cc * 65536 + (2 * xg + i2) * 1024 + (2 * yg + j2) * 16 + 2 * zg + k2];
                ushort hh, ll; f2hl(v, &hh, &ll);
                AsH[r][kk] = hh; AsL[r][kk] = ll;
            }
            for (int u = tid; u < 1024; u += 512) {
                int n = u >> 3, g = u & 7;
                *(uint4*)&BsH[n][g * 8] = *(const uint4*)&P.wH[W_PE + n * 128 + kc + g * 8];
                *(uint4*)&BsL[n][g * 8] = *(const uint4*)&P.wL[W_PE + n * 128 + kc + g * 8];
            }
            __syncthreads();
#pragma unroll
            for (int ks_ = 0; ks_ < 64; ks_ += 32) {
                const int kk = ks_ + q * 8;
                bf16x8 bh = *(const bf16x8*)&BsH[wv * 16 + ln][kk];
                bf16x8 bl = *(const bf16x8*)&BsL[wv * 16 + ln][kk];
#pragma unroll
                for (int rb = 0; rb < 2; ++rb) {
                    bf16x8 ah = *(const bf16x8*)&AsH[rb * 16 + ln][kk];
                    bf16x8 al = *(const bf16x8*)&AsL[rb * 16 + ln][kk];
                    acc[rb] = __builtin_amdgcn_mfma_f32_16x16x32_bf16(ah, bh, acc[rb], 0, 0, 0);
                    acc[rb] = __builtin_amdgcn_mfma_f32_16x16x32_bf16(ah, bl, acc[rb], 0, 0, 0);
                    acc[rb] = __builtin_amdgcn_mfma_f32_16x16x32_bf16(al, bh, acc[rb], 0, 0, 0);
                }
            }
        }
        __syncthreads();
#pragma unroll
        for (int rb = 0; rb < 2; ++rb) {
#pragma unroll
            for (int r = 0; r < 4; ++r) {
                int row = rb * 16 + q * 4 + r;
                int col = wv * 16 + ln;
                int l = mb + row;
                float rho = (float)l * (1.0f / 8191.0f);
                int band = min(7, (int)(rho * 8.0f));
                Cs[row][col] = acc[rb][r] + P.pe_b[col] + P.cond_band[band * 128 + col]
                               + rho * P.cond_rad[col] + P.mbuf[l] * P.cond_mask[col];
            }
        }
        __syncthreads();
        {
            int row = tid >> 4, j = tid & 15;
            int l = mb + row;
            float v8[8];
            float s = 0.f, s2 = 0.f;
#pragma unroll
            for (int i = 0; i < 8; ++i) {
                float v = Cs[row][j * 8 + i];
                v8[i] = v; s += v; s2 += v * v;
            }
#pragma unroll
            for (int o = 1; o < 16; o <<= 1) { s += __shfl_xor(s, o, 16); s2 += __shfl_xor(s2, o, 16); }
            float mu = s * (1.f / 128.f);
            float var = s2 * (1.f / 128.f) - mu * mu;
            float rstd = rsqrtf(fmaxf(var, 0.f) + 1e-5f);
            float hv[8];
            s = 0.f; s2 = 0.f;
#pragma unroll
            for (int i = 0; i < 8; ++i) {
                int col = j * 8 + i;
                float h = (v8[i] - mu) * rstd * P.ln_g[col] + P.ln_b[col];
                hv[i] = h; s += h; s2 += h * h;
            }
#pragma unroll
            for (int i = 0; i < 8; i += 4)
                *(float4*)&P.h_[(size_t)l * 128 + j * 8 + i] = make_float4(hv[i], hv[i + 1], hv[i + 2], hv[i + 3]);
#pragma unroll
            for (int o = 1; o < 16; o <<= 1) { s += __shfl_xor(s, o, 16); s2 += __shfl_xor(s2, o, 16); }
            mu = s * (1.f / 128.f);
            var = s2 * (1.f / 128.f) - mu * mu;
            rstd = rsqrtf(fmaxf(var, 0.f) + 1e-5f);
            union { ushort u[8]; uint4 v4; } oh, ol;
#pragma unroll
            for (int i = 0; i < 8; ++i) {
                int col = j * 8 + i;
                float o2 = (hv[i] - mu) * rstd * P.fn_g[col] + P.fn_b[col];
                ushort hh, ll; f2hl(o2, &hh, &ll);
                oh.u[i] = hh; ol.u[i] = ll;
            }
            *(uint4*)&P.hnH[(size_t)l * 128 + j * 8] = oh.v4;
            *(uint4*)&P.hnL[(size_t)l * 128 + j * 8] = ol.v4;
        }
    }
    gg.sync();

    // ================= P2: Win GEMM (64x128 tiles, 2 iters) -> xp / sz ===========
    {
        ushort (*AsH)[72] = (ushort(*)[72])(smem);
        ushort (*AsL)[72] = (ushort(*)[72])(smem + 9216);
        ushort (*BsH)[72] = (ushort(*)[72])(smem + 18432);
        ushort (*BsL)[72] = (ushort(*)[72])(smem + 36864);
        const int lane = tid & 63, wave = tid >> 6;
        const int wm2 = wave & 1, wn4 = wave >> 1;
        const int ln = lane & 15, q = lane >> 4;
        for (int it = 0; it < 2; ++it) {
            int t = b + it * 256;
            int mb = (t & 127) * 64, nb = (t >> 7) * 128;
            f32x4 acc[2][2];
#pragma unroll
            for (int rb = 0; rb < 2; ++rb)
#pragma unroll
                for (int cb = 0; cb < 2; ++cb) acc[rb][cb] = (f32x4){0.f, 0.f, 0.f, 0.f};
            for (int kc = 0; kc < 128; kc += 64) {
                __syncthreads();
                {
                    int u = tid;   // 512 vec8 loads (64 rows x 8)
                    int r = u >> 3, g = u & 7;
                    size_t go = (size_t)(mb + r) * 128 + kc + g * 8;
                    *(uint4*)&AsH[r][g * 8] = *(const uint4*)&P.hnH[go];
                    *(uint4*)&AsL[r][g * 8] = *(const uint4*)&P.hnL[go];
                }
                for (int u = tid; u < 1024; u += 512) {
                    int n = u >> 3, g = u & 7;
                    size_t go = (size_t)(W_WIN) + (size_t)(nb + n) * 128 + kc + g * 8;
                    *(uint4*)&BsH[n][g * 8] = *(const uint4*)&P.wH[go];
                    *(uint4*)&BsL[n][g * 8] = *(const uint4*)&P.wL[go];
                }
                __syncthreads();
#pragma unroll
                for (int ks_ = 0; ks_ < 64; ks_ += 32) {
                    const int kk = ks_ + q * 8;
                    bf16x8 ah[2], al[2], bh[2], bl[2];
#pragma unroll
                    for (int rb = 0; rb < 2; ++rb) {
                        ah[rb] = *(const bf16x8*)&AsH[wm2 * 32 + rb * 16 + ln][kk];
                        al[rb] = *(const bf16x8*)&AsL[wm2 * 32 + rb * 16 + ln][kk];
                    }
#pragma unroll
                    for (int cb = 0; cb < 2; ++cb) {
                        bh[cb] = *(const bf16x8*)&BsH[wn4 * 32 + cb * 16 + ln][kk];
                        bl[cb] = *(const bf16x8*)&BsL[wn4 * 32 + cb * 16 + ln][kk];
                    }
#pragma unroll
                    for (int rb = 0; rb < 2; ++rb)
#pragma unroll
                        for (int cb = 0; cb < 2; ++cb) {
                            acc[rb][cb] = __builtin_amdgcn_mfma_f32_16x16x32_bf16(ah[rb], bh[cb], acc[rb][cb], 0, 0, 0);
                            acc[rb][cb] = __builtin_amdgcn_mfma_f32_16x16x32_bf16(ah[rb], bl[cb], acc[rb][cb], 0, 0, 0);
                            acc[rb][cb] = __builtin_amdgcn_mfma_f32_16x16x32_bf16(al[rb], bh[cb], acc[rb][cb], 0, 0, 0);
                        }
                }
            }
#pragma unroll
            for (int rb = 0; rb < 2; ++rb)
#pragma unroll
                for (int cb = 0; cb < 2; ++cb)
#pragma unroll
                    for (int r = 0; r < 4; ++r) {
                        int l = mb + wm2 * 32 + rb * 16 + q * 4 + r;
                        int col = nb + wn4 * 32 + cb * 16 + ln;
                        float v = acc[rb][cb][r] + P.bin_[col];
                        if (col < 256) {
                            P.xp[(size_t)l * 256 + col] = v;
                        } else {
                            P.sz[(size_t)l * 256 + (col - 256)] = v * sigm(v);
                        }
                    }
        }
    }
    gg.sync();

    // ================= P3: conv (4-tap causal) + SiLU -> xc ======================
    for (int id = gtid; id < 524288; id += 131072) {
        int l = id >> 6, e4 = (id & 63) * 4;
        float4 cw[4];
#pragma unroll
        for (int j = 0; j < 4; ++j) cw[j] = *(const float4*)&P.convw[(e4 + j) * 4];
        float4 cb = *(const float4*)&P.convb[e4];
        float o[4] = {cb.x, cb.y, cb.z, cb.w};
#pragma unroll
        for (int k = 0; k < 4; ++k) {
            int lp = l - 3 + k;
            if (lp >= 0) {
                float4 t = *(const float4*)&P.xp[(size_t)lp * 256 + e4];
                o[0] += t.x * ((const float*)&cw[0])[k];
                o[1] += t.y * ((const float*)&cw[1])[k];
                o[2] += t.z * ((const float*)&cw[2])[k];
                o[3] += t.w * ((const float*)&cw[3])[k];
            }
        }
        float4 r;
        r.x = o[0] * sigm(o[0]);
        r.y = o[1] * sigm(o[1]);
        r.z = o[2] * sigm(o[2]);
        r.w = o[3] * sigm(o[3]);
        *(float4*)&P.xc[(size_t)l * 256 + e4] = r;
    }
    gg.sync();

    // ================= P4: proj GEMM (32x64 tiles, 5 iters) -> dt/Bm/Cm ==========
    {
        ushort (*AsH)[72] = (ushort(*)[72])(smem);
        ushort (*AsL)[72] = (ushort(*)[72])(smem + 4608);
        ushort (*BsH)[72] = (ushort(*)[72])(smem + 9216);
        ushort (*BsL)[72] = (ushort(*)[72])(smem + 18432);
        const int lane = tid & 63, wave = tid >> 6;
        const int wm2 = wave & 1, wn4 = wave >> 1;
        const int ln = lane & 15, q = lane >> 4;
        const int mb = b * 32;
        for (int it = 0; it < 5; ++it) {
            int nb = it * 64;
            f32x4 acc = (f32x4){0.f, 0.f, 0.f, 0.f};
            for (int kc = 0; kc < 256; kc += 64) {
                __syncthreads();
                {
                    int u = tid;   // 32 rows x 16 float4 = 512
                    int r = u >> 4, kq = u & 15;
                    float4 v = *(const float4*)&P.xc[(size_t)(mb + r) * 256 + kc + kq * 4];
                    union { ushort u[4]; uint2 v2; } hh, ll;
                    f2hl(v.x, &hh.u[0], &ll.u[0]); f2hl(v.y, &hh.u[1], &ll.u[1]);
                    f2hl(v.z, &hh.u[2], &ll.u[2]); f2hl(v.w, &hh.u[3], &ll.u[3]);
                    *(uint2*)&AsH[r][kq * 4] = hh.v2;
                    *(uint2*)&AsL[r][kq * 4] = ll.v2;
                }
                {
                    int u = tid;   // 64 rows x 8 vec8 = 512
                    int n = u >> 3, g = u & 7;
                    size_t go = (size_t)(W_PROJ) + (size_t)(nb + n) * 256 + kc + g * 8;
                    *(uint4*)&BsH[n][g * 8] = *(const uint4*)&P.wH[go];
                    *(uint4*)&BsL[n][g * 8] = *(const uint4*)&P.wL[go];
                }
                __syncthreads();
#pragma unroll
                for (int ks_ = 0; ks_ < 64; ks_ += 32) {
                    const int kk = ks_ + q * 8;
                    bf16x8 ah = *(const bf16x8*)&AsH[wm2 * 16 + ln][kk];
                    bf16x8 al = *(const bf16x8*)&AsL[wm2 * 16 + ln][kk];
                    bf16x8 bh = *(const bf16x8*)&BsH[wn4 * 16 + ln][kk];
                    bf16x8 bl = *(const bf16x8*)&BsL[wn4 * 16 + ln][kk];
                    acc = __builtin_amdgcn_mfma_f32_16x16x32_bf16(ah, bh, acc, 0, 0, 0);
                    acc = __builtin_amdgcn_mfma_f32_16x16x32_bf16(ah, bl, acc, 0, 0, 0);
                    acc = __builtin_amdgcn_mfma_f32_16x16x32_bf16(al, bh, acc, 0, 0, 0);
                }
            }
#pragma unroll
            for (int r = 0; r < 4; ++r) {
                int l = mb + wm2 * 16 + q * 4 + r;
                int col = nb + wn4 * 16 + ln;
                float v = acc[r];
                float rho = (float)l * (1.0f / 8191.0f);
                int band = min(7, (int)(rho * 8.0f));
                float mv = P.mbuf[l];
                if (col < 256) {
                    float sc0 = 2.0f * sigm(P.edt[band] + P.wr[0] * rho + P.wm[0] * mv);
                    float v2 = v + P.bdt[col];
                    float sp = (v2 > 20.f) ? v2 : log1pf(expf(v2));
                    P.dt[(size_t)l * 256 + col] = sp * sc0;
                } else if (col < 272) {
                    float sc1 = 2.0f * sigm(P.eB[band] + P.wr[1] * rho + P.wm[1] * mv);
                    P.Bm[(size_t)l * 16 + (col - 256)] = v * sc1;
                } else if (col < 288) {
                    float sc2 = 2.0f * sigm(P.eC[band] + P.wr[2] * rho + P.wm[2] * mv);
                    P.Cm[(size_t)l * 16 + (col - 272)] = v * sc2;
                }
            }
        }
    }
    gg.sync();

    // ================= P5: scan phase 0 (two subs: dir 0/1) -> Hb, sdtb ==========
    {
        const int sub = tid >> 8, e = tid & 255;
        float (*bms)[16] = (float(*)[16])(smem + sub * 2048);
        const int c = b, dir = sub;
        for (int idx = e; idx < 512; idx += 256)
            bms[idx >> 4][idx & 15] = P.Bm[c * 512 + idx];
        float A2[16], iv[16], h[16];
#pragma unroll
        for (int n = 0; n < 16; ++n) {
            float ea = nexp2(P.Alog[e * 16 + n] * LOG2E);
            A2[n] = -ea * LOG2E;
            iv[n] = -1.0f / ea;
            h[n] = 0.f;
        }
        const int base = c * CLh;
        float cu[8], cx[8], nu[8], nx[8];
#pragma unroll
        for (int j = 0; j < 8; ++j) {
            int p = dir ? (CLh - 1 - j) : j;
            cu[j] = P.dt[(size_t)(base + p) * 256 + e];
            cx[j] = P.xc[(size_t)(base + p) * 256 + e];
        }
        __syncthreads();
        float sdt = 0.f;
#pragma unroll
        for (int g = 0; g < CLh / 8; ++g) {
            if (g + 1 < CLh / 8) {
#pragma unroll
                for (int j = 0; j < 8; ++j) {
                    int s = (g + 1) * 8 + j;
                    int p = dir ? (CLh - 1 - s) : s;
                    nu[j] = P.dt[(size_t)(base + p) * 256 + e];
                    nx[j] = P.xc[(size_t)(base + p) * 256 + e];
                }
            }
#pragma unroll
            for (int j = 0; j < 8; ++j) {
                int s = g * 8 + j;
                int p = dir ? (CLh - 1 - s) : s;
                float u = cu[j], xv = cx[j];
                union { float4 v[4]; float f[16]; } bb;
                const float4* bp = (const float4*)&bms[p][0];
                bb.v[0] = bp[0]; bb.v[1] = bp[1]; bb.v[2] = bp[2]; bb.v[3] = bp[3];
#pragma unroll
                for (int n = 0; n < 16; ++n) {
                    float a = nexp2(A2[n] * u);
                    float w = xv * bb.f[n] * iv[n];
                    h[n] = a * (h[n] + w) - w;
                }
                sdt += u;
            }
#pragma unroll
            for (int j = 0; j < 8; ++j) { cu[j] = nu[j]; cx[j] = nx[j]; }
        }
        const size_t hofs = (size_t)(dir * NCh + c) * 4096 + e * 16;
#pragma unroll
        for (int j = 0; j < 4; ++j)
            *(float4*)&P.Hb[hofs + 4 * j] = make_float4(h[4 * j], h[4 * j + 1], h[4 * j + 2], h[4 * j + 3]);
        if (dir == 0) P.sdtb[c * 256 + e] = sdt;
    }
    gg.sync();

    // ================= P6: chunk-level combine -> Hpre ===========================
    if (gtid < 8192) {
        int dir = gtid >> 12, en = gtid & 4095, e = en >> 4;
        float A2 = -nexp2(P.Alog[en] * LOG2E) * LOG2E;
        float hi = 0.f;
        for (int g = 0; g < NCh / 8; ++g) {
            float Pv[8], qv[8];
#pragma unroll
            for (int j = 0; j < 8; ++j) {
                int c = dir ? (NCh - 1 - (g * 8 + j)) : (g * 8 + j);
                Pv[j] = P.sdtb[c * 256 + e];
                qv[j] = P.Hb[(size_t)(dir * NCh + c) * 4096 + en];
            }
#pragma unroll
            for (int j = 0; j < 8; ++j) {
                int c = dir ? (NCh - 1 - (g * 8 + j)) : (g * 8 + j);
                float Pp = nexp2(A2 * Pv[j]);
                P.Hpre[(size_t)(dir * NCh + c) * 4096 + en] = hi;
                hi = Pp * hi + qv[j];
            }
        }
    }
    gg.sync();

    // ================= P7: scan phase 1 + gate -> AHo/ALo (bf16 hi/lo) ===========
    {
        const int c = b;
        const int dir = tid >> 8;
        const int e = tid & 255;
        float (*bms)[16] = (float(*)[16])(smem);
        float (*cms)[16] = (float(*)[16])(smem + 2048);
        float (*ysum)[256] = (float(*)[256])(smem + 4096);
        for (int idx = tid; idx < 512; idx += 512) {
            bms[idx >> 4][idx & 15] = P.Bm[c * 512 + idx];
            cms[idx >> 4][idx & 15] = P.Cm[c * 512 + idx];
        }
        float A2[16], iv[16], h[16];
#pragma unroll
        for (int n = 0; n < 16; ++n) {
            float ea = nexp2(P.Alog[e * 16 + n] * LOG2E);
            A2[n] = -ea * LOG2E;
            iv[n] = -1.0f / ea;
        }
        const size_t hofs = (size_t)(dir * NCh + c) * 4096 + e * 16;
#pragma unroll
        for (int j = 0; j < 4; ++j) {
            float4 hv = *(const float4*)&P.Hpre[hofs + 4 * j];
            h[4 * j] = hv.x; h[4 * j + 1] = hv.y; h[4 * j + 2] = hv.z; h[4 * j + 3] = hv.w;
        }
        const int base = c * CLh;
        float yreg[CLh];
        __syncthreads();
        if (dir == 0) {
            scan_dir<0>(P.dt, P.xc, base, e, bms, cms, A2, iv, h, yreg);
        } else {
            scan_dir<1>(P.dt, P.xc, base, e, bms, cms, A2, iv, h, yreg);
        }
        __syncthreads();
        if (dir == 0) {
#pragma unroll
            for (int l = 0; l < CLh; ++l) ysum[l][e] = yreg[l];
        }
        __syncthreads();
        if (dir == 1) {
            float dpv = P.Dp[e];
#pragma unroll
            for (int l = 0; l < CLh; ++l) {
                size_t gl = (size_t)(base + l) * 256 + e;
                float a = (ysum[l][e] + yreg[l] + dpv * P.xc[gl]) * P.sz[gl];
                ushort hh, ll; f2hl(a, &hh, &ll);
                P.AHo[gl] = hh; P.ALo[gl] = ll;
            }
        }
    }
    gg.sync();

    // ================= P8: Wout GEMM (two subs, 32x64 tiles) -> hf ===============
    {
        const int sub = tid >> 8, st = tid & 255;
        char* sm = smem + sub * 27648;
        ushort (*AsH)[72] = (ushort(*)[72])(sm);
        ushort (*AsL)[72] = (ushort(*)[72])(sm + 4608);
        ushort (*BsH)[72] = (ushort(*)[72])(sm + 9216);
        ushort (*BsL)[72] = (ushort(*)[72])(sm + 18432);
        const int lane = st & 63, wave = st >> 6;
        const int wm2 = wave & 1, wn2 = wave >> 1;
        const int ln = lane & 15, q = lane >> 4;
        const int mb = b * 32, nb = sub * 64;
        f32x4 acc[2];
        acc[0] = (f32x4){0.f, 0.f, 0.f, 0.f};
        acc[1] = (f32x4){0.f, 0.f, 0.f, 0.f};
        for (int kc = 0; kc < 256; kc += 64) {
            __syncthreads();
            {
                int u = st;      // 32 rows x 8 vec8 = 256
                int r = u >> 3, g = u & 7;
                size_t go = (size_t)(mb + r) * 256 + kc + g * 8;
                *(uint4*)&AsH[r][g * 8] = *(const uint4*)&P.AHo[go];
                *(uint4*)&AsL[r][g * 8] = *(const uint4*)&P.ALo[go];
            }
            for (int u = st; u < 512; u += 256) {
                int n = u >> 3, g = u & 7;
                size_t go = (size_t)(W_WOUT) + (size_t)(nb + n) * 256 + kc + g * 8;
                *(uint4*)&BsH[n][g * 8] = *(const uint4*)&P.wH[go];
                *(uint4*)&BsL[n][g * 8] = *(const uint4*)&P.wL[go];
            }
            __syncthreads();
#pragma unroll
            for (int ks_ = 0; ks_ < 64; ks_ += 32) {
                const int kk = ks_ + q * 8;
                bf16x8 ah = *(const bf16x8*)&AsH[wm2 * 16 + ln][kk];
                bf16x8 al = *(const bf16x8*)&AsL[wm2 * 16 + ln][kk];
#pragma unroll
                for (int cb = 0; cb < 2; ++cb) {
                    bf16x8 bh = *(const bf16x8*)&BsH[wn2 * 32 + cb * 16 + ln][kk];
                    bf16x8 bl = *(const bf16x8*)&BsL[wn2 * 32 + cb * 16 + ln][kk];
                    acc[cb] = __builtin_amdgcn_mfma_f32_16x16x32_bf16(ah, bh, acc[cb], 0, 0, 0);
                    acc[cb] = __builtin_amdgcn_mfma_f32_16x16x32_bf16(ah, bl, acc[cb], 0, 0, 0);
                    acc[cb] = __builtin_amdgcn_mfma_f32_16x16x32_bf16(al, bh, acc[cb], 0, 0, 0);
                }
            }
        }
#pragma unroll
        for (int cb = 0; cb < 2; ++cb)
#pragma unroll
            for (int r = 0; r < 4; ++r) {
                int l = mb + wm2 * 16 + q * 4 + r;
                int col = nb + wn2 * 32 + cb * 16 + ln;
                float v = acc[cb][r] + P.bout[col] + P.h_[(size_t)l * 128 + col];
                ushort hh, ll; f2hl(v, &hh, &ll);
                P.hfH[(size_t)l * 128 + col] = hh;
                P.hfL[(size_t)l * 128 + col] = ll;
            }
    }
    gg.sync();

    // ================= P9: unembed GEMM (two subs, 32x64 tiles) -> out ===========
    {
        const int sub = tid >> 8, st = tid & 255;
        char* sm = smem + sub * 27648;
        ushort (*AsH)[72] = (ushort(*)[72])(sm);
        ushort (*AsL)[72] = (ushort(*)[72])(sm + 4608);
        ushort (*BsH)[72] = (ushort(*)[72])(sm + 9216);
        ushort (*BsL)[72] = (ushort(*)[72])(sm + 18432);
        const int lane = st & 63, wave = st >> 6;
        const int wm2 = wave & 1, wn2 = wave >> 1;
        const int ln = lane & 15, q = lane >> 4;
        const int mb = b * 32, nb = sub * 64;
        f32x4 acc[2];
        acc[0] = (f32x4){0.f, 0.f, 0.f, 0.f};
        acc[1] = (f32x4){0.f, 0.f, 0.f, 0.f};
        for (int kc = 0; kc < 128; kc += 64) {
            __syncthreads();
            {
                int u = st;      // 32 rows x 8 vec8 = 256
                int r = u >> 3, g = u & 7;
                size_t go = (size_t)(mb + r) * 128 + kc + g * 8;
                *(uint4*)&AsH[r][g * 8] = *(const uint4*)&P.hfH[go];
                *(uint4*)&AsL[r][g * 8] = *(const uint4*)&P.hfL[go];
            }
            for (int u = st; u < 512; u += 256) {
                int n = u >> 3, g = u & 7;
                size_t go = (size_t)(W_PU) + (size_t)(nb + n) * 128 + kc + g * 8;
                *(uint4*)&BsH[n][g * 8] = *(const uint4*)&P.wH[go];
                *(uint4*)&BsL[n][g * 8] = *(const uint4*)&P.wL[go];
            }
            __syncthreads();
#pragma unroll
            for (int ks_ = 0; ks_ < 64; ks_ += 32) {
                const int kk = ks_ + q * 8;
                bf16x8 ah = *(const bf16x8*)&AsH[wm2 * 16 + ln][kk];
                bf16x8 al = *(const bf16x8*)&AsL[wm2 * 16 + ln][kk];
#pragma unroll
                for (int cb = 0; cb < 2; ++cb) {
                    bf16x8 bh = *(const bf16x8*)&BsH[wn2 * 32 + cb * 16 + ln][kk];
                    bf16x8 bl = *(const bf16x8*)&BsL[wn2 * 32 + cb * 16 + ln][kk];
                    acc[cb] = __builtin_amdgcn_mfma_f32_16x16x32_bf16(ah, bh, acc[cb], 0, 0, 0);
                    acc[cb] = __builtin_amdgcn_mfma_f32_16x16x32_bf16(ah, bl, acc[cb], 0, 0, 0);
                    acc[cb] = __builtin_amdgcn_mfma_f32_16x16x32_bf16(al, bh, acc[cb], 0, 0, 0);
                }
            }
        }
#pragma unroll
        for (int cb = 0; cb < 2; ++cb)
#pragma unroll
            for (int r = 0; r < 4; ++r) {
                int l = mb + wm2 * 16 + q * 4 + r;
                int col = nb + wn2 * 32 + cb * 16 + ln;
                int xg = l >> 8, yg = (l >> 3) & 31, zg = l & 7;
                int cc = col >> 3, ijk = col & 7;
                int i2 = (ijk >> 2) & 1, j2 = (ijk >> 1) & 1, k2 = ijk & 1;
                size_t idx = (size_t)((cc * 64 + 2 * xg + i2) * 64 + (2 * yg + j2)) * 16 + 2 * zg + k2;
                P.out[idx] = acc[cb][r] + P.pu_b[cc] + P.ks[idx];
            }
    }
}

// ---------------------------------------------------------------------------
extern "C" void kernel_launch(void* const* d_in, const int* in_sizes, int n_in,
                              void* d_out, int out_size, void* d_ws, size_t ws_size,
                              hipStream_t stream) {
    KParams P;
    P.ks    = (const float*)d_in[0];
    P.mask  = (const float*)d_in[1];
    P.pe_w  = (const float*)d_in[2];
    P.pe_b  = (const float*)d_in[3];
    P.pu_w  = (const float*)d_in[4];
    P.pu_b  = (const float*)d_in[5];
    P.ln_g  = (const float*)d_in[6];
    P.ln_b  = (const float*)d_in[7];
    P.fn_g  = (const float*)d_in[8];
    P.fn_b  = (const float*)d_in[9];
    P.cond_band = (const float*)d_in[10];
    P.cond_rad  = (const float*)d_in[11];
    P.cond_mask = (const float*)d_in[12];
    P.Win   = (const float*)d_in[13];
    P.bin_  = (const float*)d_in[14];
    P.convw = (const float*)d_in[15];
    P.convb = (const float*)d_in[16];
    P.Wx    = (const float*)d_in[17];
    P.Wdt   = (const float*)d_in[18];
    P.bdt   = (const float*)d_in[19];
    P.Alog  = (const float*)d_in[20];
    P.Dp    = (const float*)d_in[21];
    P.Wout  = (const float*)d_in[22];
    P.bout  = (const float*)d_in[23];
    P.edt   = (const float*)d_in[24];
    P.eB    = (const float*)d_in[25];
    P.eC    = (const float*)d_in[26];
    P.wr    = (const float*)d_in[27];
    P.wm    = (const float*)d_in[28];
    P.out   = (float*)d_out;

    char* base = (char*)d_ws;
    size_t o = 0;
    auto alloc = [&](size_t bytes) { char* p = base + o; o += (bytes + 255) & ~(size_t)255; return p; };
    P.mbuf = (float*)alloc(32768);
    P.wH   = (ushort*)alloc(W_TOT * 2);
    P.wL   = (ushort*)alloc(W_TOT * 2);
    P.h_   = (float*)alloc(4194304);
    P.hnH  = (ushort*)alloc(2097152);
    P.hnL  = (ushort*)alloc(2097152);
    P.xp   = (float*)alloc(8388608);
    P.sz   = (float*)alloc(8388608);
    P.xc   = (float*)alloc(8388608);
    P.dt   = (float*)alloc(8388608);
    P.Bm   = (float*)alloc(524288);
    P.Cm   = (float*)alloc(524288);
    P.Hb   = (float*)alloc(8388608);
    P.Hpre = (float*)alloc(8388608);
    P.sdtb = (float*)alloc(262144);
    P.AHo  = (ushort*)alloc(4194304);
    P.ALo  = (ushort*)alloc(4194304);
    P.hfH  = (ushort*)alloc(2097152);
    P.hfL  = (ushort*)alloc(2097152);

    void* args[] = { (void*)&P };
    hipLaunchCooperativeKernel((const void*)mega_k, dim3(256), dim3(512), args, 0, stream);
}

// Round 11
// 237.104 us; speedup vs baseline: 2.3139x; 2.3139x over previous
//
#include <hip/hip_runtime.h>
#include <hip/hip_bf16.h>

#define L_TOK 8192
#define NCh 256   // scan chunks
#define CLh 32    // chunk length
#define LOG2E 1.44269504088896f

typedef short bf16x8 __attribute__((ext_vector_type(8)));
typedef float f32x4 __attribute__((ext_vector_type(4)));

static __device__ __forceinline__ float nexp2(float x) {
#if __has_builtin(__builtin_amdgcn_exp2f)
    return __builtin_amdgcn_exp2f(x);
#else
    return exp2f(x);
#endif
}
static __device__ __forceinline__ float sigm(float x) {
    return 1.f / (1.f + nexp2(-x * LOG2E));
}
static __device__ __forceinline__ ushort f2bf(float x) {
    union { float f; uint u; } v; v.f = x;
    uint r = v.u + 0x7fffu + ((v.u >> 16) & 1u);
    return (ushort)(r >> 16);
}
static __device__ __forceinline__ float bf2f(ushort h) {
    union { float f; uint u; } v; v.u = ((uint)h) << 16;
    return v.f;
}
static __device__ __forceinline__ void f2hl(float x, ushort* hi, ushort* lo) {
    ushort h = f2bf(x);
    *hi = h;
    *lo = f2bf(x - bf2f(h));
}

// weight regions in wH/wL (ushort elems), all K-major [n][k]:
#define W_PE   0
#define W_WIN  16384
#define W_WOUT 81920
#define W_PU   114688
#define W_PROJ 131072
#define W_TOT  212992

// ---------------------------------------------------------------------------
// prep: weights -> bf16 hi/lo (with transposes + Wx@Wdt fusion) ; maskpool
__global__ __launch_bounds__(256) void prep_k(const float* __restrict__ pe_w, const float* __restrict__ Win,
                                              const float* __restrict__ Wx, const float* __restrict__ Wdt,
                                              const float* __restrict__ Wout, const float* __restrict__ pu_w,
                                              const float* __restrict__ mask,
                                              ushort* __restrict__ wH, ushort* __restrict__ wL,
                                              float* __restrict__ mbuf) {
    int b = blockIdx.x;
    if (b >= 832) {  // maskpool
        int l = (b - 832) * 256 + threadIdx.x;
        int xg = l >> 8, yg = (l >> 3) & 31, zg = l & 7;
        float s = 0.f;
        for (int i2 = 0; i2 < 2; ++i2)
            for (int j2 = 0; j2 < 2; ++j2)
                for (int k2 = 0; k2 < 2; ++k2)
                    s += mask[(2 * xg + i2) * 1024 + (2 * yg + j2) * 16 + 2 * zg + k2];
        s *= 0.125f;
        mbuf[l] = fminf(fmaxf(s, 0.f), 1.f);
        return;
    }
    int i = b * 256 + threadIdx.x;  // < 212992
    float v;
    if (i < 16384) {
        v = pe_w[i];
    } else if (i < 81920) {
        int j = i - 16384; int n = j >> 7, k = j & 127;
        v = Win[k * 512 + n];
    } else if (i < 114688) {
        int j = i - 81920; int n = j >> 8, k = j & 255;
        v = Wout[k * 128 + n];
    } else if (i < 131072) {
        int j = i - 114688; int n = j >> 7, k = j & 127;
        v = pu_w[k * 128 + n];
    } else {
        int j = i - 131072; int n = j >> 8, k = j & 255;
        if (n < 256) {
            float s = 0.f;
#pragma unroll
            for (int r = 0; r < 8; ++r) s += Wx[k * 40 + r] * Wdt[r * 256 + n];
            v = s;
        } else if (n < 288) {
            v = Wx[k * 40 + 8 + (n - 256)];
        } else {
            v = 0.f;
        }
    }
    ushort h, lo; f2hl(v, &h, &lo);
    wH[i] = h; wL[i] = lo;
}

// ---------------------------------------------------------------------------
// fused: gather (LDS-staged, coalesced) -> embed GEMM (+pe_b+cond) -> LN2
// tile 16 x 128 (full N), 512 blocks, 256 threads.
__global__ __launch_bounds__(256) void embed_ln_k(const float* __restrict__ ks,
                                                  const ushort* __restrict__ wH, const ushort* __restrict__ wL,
                                                  const float* __restrict__ pe_b, const float* __restrict__ cond_band,
                                                  const float* __restrict__ cond_rad, const float* __restrict__ cond_mask,
                                                  const float* __restrict__ mbuf,
                                                  const float* __restrict__ ln_g, const float* __restrict__ ln_b,
                                                  const float* __restrict__ fn_g, const float* __restrict__ fn_b,
                                                  float* __restrict__ h_,
                                                  ushort* __restrict__ hnH, ushort* __restrict__ hnL) {
    __shared__ __align__(16) char smem[50176];
    ushort (*AsH)[72] = (ushort(*)[72])(smem);             // 16x72
    ushort (*AsL)[72] = (ushort(*)[72])(smem + 2304);
    ushort (*BsH)[72] = (ushort(*)[72])(smem + 4608);      // 128x72
    ushort (*BsL)[72] = (ushort(*)[72])(smem + 23040);     // ..41472
    float*  ksb       = (float*)(smem + 41472);            // 2176 floats (128 segs x 17)
    float  (*Cs)[132] = (float(*)[132])(smem);             // 16x132 (reuse after MFMA)

    const int tid = threadIdx.x;
    const int lane = tid & 63, wn = tid >> 6;
    const int ln = lane & 15, q = lane >> 4;
    const int mb = blockIdx.x * 16;
    const int xg = mb >> 8, yg0 = (mb >> 3) & 31;

    // coalesced stage of the block's kspace footprint:
    // seg = (cc*2+i2)*4 + yy  (yy = y-plane 0..3), 16 z-floats per seg, stride 17
    for (int v = tid; v < 512; v += 256) {
        int seg = v >> 2, zq = v & 3;
        int cc = seg >> 3, i2 = (seg >> 2) & 1, yy = seg & 3;
        float4 t4 = *(const float4*)&ks[cc * 65536 + (2 * xg + i2) * 1024 + (2 * yg0 + yy) * 16 + zq * 4];
        int la = seg * 17 + zq * 4;
        ksb[la] = t4.x; ksb[la + 1] = t4.y; ksb[la + 2] = t4.z; ksb[la + 3] = t4.w;
    }

    f32x4 acc[2];
    acc[0] = (f32x4){0.f, 0.f, 0.f, 0.f};
    acc[1] = (f32x4){0.f, 0.f, 0.f, 0.f};

    for (int kc = 0; kc < 128; kc += 64) {
        __syncthreads();
        for (int u = tid; u < 1024; u += 256) {
            int r = u >> 6, kk = u & 63;
            int k = kc + kk;
            int cc = k >> 3, ijk = k & 7;
            int i2 = (ijk >> 2) & 1, j2 = (ijk >> 1) & 1, k2 = ijk & 1;
            int seg = (cc * 2 + i2) * 4 + (r >> 3) * 2 + j2;
            float v = ksb[seg * 17 + (r & 7) * 2 + k2];
            ushort hh, ll; f2hl(v, &hh, &ll);
            AsH[r][kk] = hh; AsL[r][kk] = ll;
        }
        for (int u = tid; u < 1024; u += 256) {
            int n = u >> 3, g = u & 7;
            *(uint4*)&BsH[n][g * 8] = *(const uint4*)&wH[W_PE + n * 128 + kc + g * 8];
            *(uint4*)&BsL[n][g * 8] = *(const uint4*)&wL[W_PE + n * 128 + kc + g * 8];
        }
        __syncthreads();
#pragma unroll
        for (int ks_ = 0; ks_ < 64; ks_ += 32) {
            const int kk = ks_ + q * 8;
            bf16x8 ah = *(const bf16x8*)&AsH[ln][kk];
            bf16x8 al = *(const bf16x8*)&AsL[ln][kk];
#pragma unroll
            for (int cb = 0; cb < 2; ++cb) {
                bf16x8 bh = *(const bf16x8*)&BsH[wn * 32 + cb * 16 + ln][kk];
                bf16x8 bl = *(const bf16x8*)&BsL[wn * 32 + cb * 16 + ln][kk];
                acc[cb] = __builtin_amdgcn_mfma_f32_16x16x32_bf16(ah, bh, acc[cb], 0, 0, 0);
                acc[cb] = __builtin_amdgcn_mfma_f32_16x16x32_bf16(ah, bl, acc[cb], 0, 0, 0);
                acc[cb] = __builtin_amdgcn_mfma_f32_16x16x32_bf16(al, bh, acc[cb], 0, 0, 0);
            }
        }
    }
    __syncthreads();
#pragma unroll
    for (int cb = 0; cb < 2; ++cb) {
#pragma unroll
        for (int r = 0; r < 4; ++r) {
            int row = q * 4 + r;
            int col = wn * 32 + cb * 16 + ln;
            int l = mb + row;
            float rho = (float)l * (1.0f / 8191.0f);
            int band = min(7, (int)(rho * 8.0f));
            Cs[row][col] = acc[cb][r] + pe_b[col] + cond_band[band * 128 + col]
                           + rho * cond_rad[col] + mbuf[l] * cond_mask[col];
        }
    }
    __syncthreads();
    {
        int row = tid >> 4, j = tid & 15;
        int l = mb + row;
        float v8[8];
        float s = 0.f, s2 = 0.f;
#pragma unroll
        for (int i = 0; i < 8; ++i) {
            float v = Cs[row][j * 8 + i];
            v8[i] = v; s += v; s2 += v * v;
        }
#pragma unroll
        for (int o = 1; o < 16; o <<= 1) { s += __shfl_xor(s, o, 16); s2 += __shfl_xor(s2, o, 16); }
        float mu = s * (1.f / 128.f);
        float var = s2 * (1.f / 128.f) - mu * mu;
        float rstd = rsqrtf(fmaxf(var, 0.f) + 1e-5f);
        float hv[8];
        s = 0.f; s2 = 0.f;
#pragma unroll
        for (int i = 0; i < 8; ++i) {
            int col = j * 8 + i;
            float h = (v8[i] - mu) * rstd * ln_g[col] + ln_b[col];
            hv[i] = h; s += h; s2 += h * h;
        }
#pragma unroll
        for (int i = 0; i < 8; i += 4)
            *(float4*)&h_[(size_t)l * 128 + j * 8 + i] = make_float4(hv[i], hv[i + 1], hv[i + 2], hv[i + 3]);
#pragma unroll
        for (int o = 1; o < 16; o <<= 1) { s += __shfl_xor(s, o, 16); s2 += __shfl_xor(s2, o, 16); }
        mu = s * (1.f / 128.f);
        var = s2 * (1.f / 128.f) - mu * mu;
        rstd = rsqrtf(fmaxf(var, 0.f) + 1e-5f);
        union { ushort u[8]; uint4 v4; } oh, ol;
#pragma unroll
        for (int i = 0; i < 8; ++i) {
            int col = j * 8 + i;
            float o2 = (hv[i] - mu) * rstd * fn_g[col] + fn_b[col];
            ushort hh, ll; f2hl(o2, &hh, &ll);
            oh.u[i] = hh; ol.u[i] = ll;
        }
        *(uint4*)&hnH[(size_t)l * 128 + j * 8] = oh.v4;
        *(uint4*)&hnL[(size_t)l * 128 + j * 8] = ol.v4;
    }
}

// ---------------------------------------------------------------------------
// Win GEMM: 64x64 tiles, grid (128,8) = 1024 blocks. xp raw / sz silu split.
__global__ __launch_bounds__(256) void win_k(const ushort* __restrict__ Ah, const ushort* __restrict__ Al,
                                             const ushort* __restrict__ wH, const ushort* __restrict__ wL,
                                             const float* __restrict__ bin_,
                                             float* __restrict__ xp, float* __restrict__ sz) {
    __shared__ ushort AsH[64][72], AsL[64][72];
    __shared__ ushort BsH[64][72], BsL[64][72];
    const int tid = threadIdx.x;
    const int lane = tid & 63, wave = tid >> 6;
    const int wm = wave & 1, wn = wave >> 1;
    const int ln = lane & 15, q = lane >> 4;
    const int mb = blockIdx.x * 64, nb = blockIdx.y * 64;

    f32x4 acc[2][2];
#pragma unroll
    for (int rb = 0; rb < 2; ++rb)
#pragma unroll
        for (int cb = 0; cb < 2; ++cb) acc[rb][cb] = (f32x4){0.f, 0.f, 0.f, 0.f};

    for (int kc = 0; kc < 128; kc += 64) {
        __syncthreads();
        for (int u = tid; u < 512; u += 256) {
            int r = u >> 3, g = u & 7;
            size_t go = (size_t)(mb + r) * 128 + kc + g * 8;
            *(uint4*)&AsH[r][g * 8] = *(const uint4*)&Ah[go];
            *(uint4*)&AsL[r][g * 8] = *(const uint4*)&Al[go];
        }
        for (int u = tid; u < 512; u += 256) {
            int n = u >> 3, g = u & 7;
            size_t go = (size_t)(W_WIN) + (size_t)(nb + n) * 128 + kc + g * 8;
            *(uint4*)&BsH[n][g * 8] = *(const uint4*)&wH[go];
            *(uint4*)&BsL[n][g * 8] = *(const uint4*)&wL[go];
        }
        __syncthreads();
#pragma unroll
        for (int ks_ = 0; ks_ < 64; ks_ += 32) {
            const int kk = ks_ + q * 8;
            bf16x8 ah[2], al[2], bh[2], bl[2];
#pragma unroll
            for (int rb = 0; rb < 2; ++rb) {
                ah[rb] = *(const bf16x8*)&AsH[wm * 32 + rb * 16 + ln][kk];
                al[rb] = *(const bf16x8*)&AsL[wm * 32 + rb * 16 + ln][kk];
            }
#pragma unroll
            for (int cb = 0; cb < 2; ++cb) {
                bh[cb] = *(const bf16x8*)&BsH[wn * 32 + cb * 16 + ln][kk];
                bl[cb] = *(const bf16x8*)&BsL[wn * 32 + cb * 16 + ln][kk];
            }
#pragma unroll
            for (int rb = 0; rb < 2; ++rb)
#pragma unroll
                for (int cb = 0; cb < 2; ++cb) {
                    acc[rb][cb] = __builtin_amdgcn_mfma_f32_16x16x32_bf16(ah[rb], bh[cb], acc[rb][cb], 0, 0, 0);
                    acc[rb][cb] = __builtin_amdgcn_mfma_f32_16x16x32_bf16(ah[rb], bl[cb], acc[rb][cb], 0, 0, 0);
                    acc[rb][cb] = __builtin_amdgcn_mfma_f32_16x16x32_bf16(al[rb], bh[cb], acc[rb][cb], 0, 0, 0);
                }
        }
    }
#pragma unroll
    for (int rb = 0; rb < 2; ++rb)
#pragma unroll
        for (int cb = 0; cb < 2; ++cb)
#pragma unroll
            for (int r = 0; r < 4; ++r) {
                int l = mb + wm * 32 + rb * 16 + q * 4 + r;
                int col = nb + wn * 32 + cb * 16 + ln;
                float v = acc[rb][cb][r] + bin_[col];
                if (col < 256) {
                    xp[(size_t)l * 256 + col] = v;
                } else {
                    sz[(size_t)l * 256 + (col - 256)] = v * sigm(v);
                }
            }
}

// ---------------------------------------------------------------------------
// proj GEMM with conv+SiLU fused in front. 512 threads, grid 256 (32 rows each).
// A (=xc) staged ONCE for all K=256 into [264]-stride LDS; xc also written out.
__global__ __launch_bounds__(512) void proj_k(const float* __restrict__ xp,
                                              const float* __restrict__ convw, const float* __restrict__ convb,
                                              const ushort* __restrict__ wH, const ushort* __restrict__ wL,
                                              const float* __restrict__ bdt, const float* __restrict__ mbuf,
                                              const float* __restrict__ edt, const float* __restrict__ eB,
                                              const float* __restrict__ eC, const float* __restrict__ wr,
                                              const float* __restrict__ wm,
                                              float* __restrict__ xc, float* __restrict__ dt,
                                              float* __restrict__ Bm, float* __restrict__ Cm) {
    __shared__ __align__(16) char smem[52224];
    ushort (*AsH)[264] = (ushort(*)[264])(smem);            // 32x264x2 = 16896
    ushort (*AsL)[264] = (ushort(*)[264])(smem + 16896);    // ..33792
    ushort (*BsH)[72]  = (ushort(*)[72])(smem + 33792);     // 64x72x2 = 9216
    ushort (*BsL)[72]  = (ushort(*)[72])(smem + 43008);     // ..52224
    const int tid = threadIdx.x;
    const int mb = blockIdx.x * 32;

    // ---- conv (4-tap causal) + SiLU, sliding window; -> xc global + LDS hi/lo
    {
        const int cg = tid & 63;       // col group: cols cg*4..+3
        const int rg = tid >> 6;       // row group: rows rg*4..+3
        const int c0 = cg * 4;
        float4 cb4 = *(const float4*)&convb[c0];
        float4 cw0 = *(const float4*)&convw[(c0 + 0) * 4];
        float4 cw1 = *(const float4*)&convw[(c0 + 1) * 4];
        float4 cw2 = *(const float4*)&convw[(c0 + 2) * 4];
        float4 cw3 = *(const float4*)&convw[(c0 + 3) * 4];
        const int lbase = mb + rg * 4;
        float4 zero = make_float4(0.f, 0.f, 0.f, 0.f);
        float4 x0 = (lbase - 3 >= 0) ? *(const float4*)&xp[(size_t)(lbase - 3) * 256 + c0] : zero;
        float4 x1 = (lbase - 2 >= 0) ? *(const float4*)&xp[(size_t)(lbase - 2) * 256 + c0] : zero;
        float4 x2 = (lbase - 1 >= 0) ? *(const float4*)&xp[(size_t)(lbase - 1) * 256 + c0] : zero;
#pragma unroll
        for (int rr = 0; rr < 4; ++rr) {
            int l = lbase + rr;
            float4 x3 = *(const float4*)&xp[(size_t)l * 256 + c0];
            float o0 = cb4.x + x0.x * cw0.x + x1.x * cw0.y + x2.x * cw0.z + x3.x * cw0.w;
            float o1 = cb4.y + x0.y * cw1.x + x1.y * cw1.y + x2.y * cw1.z + x3.y * cw1.w;
            float o2 = cb4.z + x0.z * cw2.x + x1.z * cw2.y + x2.z * cw2.z + x3.z * cw2.w;
            float o3 = cb4.w + x0.w * cw3.x + x1.w * cw3.y + x2.w * cw3.z + x3.w * cw3.w;
            o0 *= sigm(o0); o1 *= sigm(o1); o2 *= sigm(o2); o3 *= sigm(o3);
            *(float4*)&xc[(size_t)l * 256 + c0] = make_float4(o0, o1, o2, o3);
            union { ushort u[4]; uint2 v2; } hh, ll;
            f2hl(o0, &hh.u[0], &ll.u[0]); f2hl(o1, &hh.u[1], &ll.u[1]);
            f2hl(o2, &hh.u[2], &ll.u[2]); f2hl(o3, &hh.u[3], &ll.u[3]);
            int row = l - mb;
            *(uint2*)&AsH[row][c0] = hh.v2;
            *(uint2*)&AsL[row][c0] = ll.v2;
            x0 = x1; x1 = x2; x2 = x3;
        }
    }
    __syncthreads();

    // ---- GEMM 32x64 per iter, 5 iters, 8 waves (wm2 row-half, wn4 col-16)
    const int lane = tid & 63, wave = tid >> 6;
    const int wm2 = wave & 1, wn4 = wave >> 1;
    const int ln = lane & 15, q = lane >> 4;
    for (int it = 0; it < 5; ++it) {
        int nb = it * 64;
        f32x4 acc = (f32x4){0.f, 0.f, 0.f, 0.f};
        for (int kc = 0; kc < 256; kc += 64) {
            __syncthreads();
            {
                int u = tid;   // 64 n-rows x 8 vec8 = 512
                int n = u >> 3, g = u & 7;
                size_t go = (size_t)(W_PROJ) + (size_t)(nb + n) * 256 + kc + g * 8;
                *(uint4*)&BsH[n][g * 8] = *(const uint4*)&wH[go];
                *(uint4*)&BsL[n][g * 8] = *(const uint4*)&wL[go];
            }
            __syncthreads();
#pragma unroll
            for (int ks_ = 0; ks_ < 64; ks_ += 32) {
                const int kka = kc + ks_ + q * 8;
                const int kkb = ks_ + q * 8;
                bf16x8 ah = *(const bf16x8*)&AsH[wm2 * 16 + ln][kka];
                bf16x8 al = *(const bf16x8*)&AsL[wm2 * 16 + ln][kka];
                bf16x8 bh = *(const bf16x8*)&BsH[wn4 * 16 + ln][kkb];
                bf16x8 bl = *(const bf16x8*)&BsL[wn4 * 16 + ln][kkb];
                acc = __builtin_amdgcn_mfma_f32_16x16x32_bf16(ah, bh, acc, 0, 0, 0);
                acc = __builtin_amdgcn_mfma_f32_16x16x32_bf16(ah, bl, acc, 0, 0, 0);
                acc = __builtin_amdgcn_mfma_f32_16x16x32_bf16(al, bh, acc, 0, 0, 0);
            }
        }
#pragma unroll
        for (int r = 0; r < 4; ++r) {
            int l = mb + wm2 * 16 + q * 4 + r;
            int col = nb + wn4 * 16 + ln;
            float v = acc[r];
            float rho = (float)l * (1.0f / 8191.0f);
            int band = min(7, (int)(rho * 8.0f));
            float mv = mbuf[l];
            if (col < 256) {
                float sc0 = 2.0f * sigm(edt[band] + wr[0] * rho + wm[0] * mv);
                float v2 = v + bdt[col];
                float sp = (v2 > 20.f) ? v2 : log1pf(expf(v2));
                dt[(size_t)l * 256 + col] = sp * sc0;
            } else if (col < 272) {
                float sc1 = 2.0f * sigm(eB[band] + wr[1] * rho + wm[1] * mv);
                Bm[(size_t)l * 16 + (col - 256)] = v * sc1;
            } else if (col < 288) {
                float sc2 = 2.0f * sigm(eC[band] + wr[2] * rho + wm[2] * mv);
                Cm[(size_t)l * 16 + (col - 272)] = v * sc2;
            }
        }
    }
}

// ---------------------------------------------------------------------------
// scan phase 0: chunk-local end states -> Hb, fwd chunk dt-sums -> sdtb
__global__ __launch_bounds__(256) void scan0_k(const float* __restrict__ dt, const float* __restrict__ xc,
                                               const float* __restrict__ Bm, const float* __restrict__ Alog,
                                               float* __restrict__ Hb, float* __restrict__ sdtb) {
    const int c = blockIdx.x, dir = blockIdx.y, e = threadIdx.x;
    __shared__ float bms[CLh][16];
    for (int idx = e; idx < CLh * 16; idx += 256)
        bms[idx >> 4][idx & 15] = Bm[c * (CLh * 16) + idx];
    float A2[16], iv[16], h[16];
#pragma unroll
    for (int n = 0; n < 16; ++n) {
        float ea = nexp2(Alog[e * 16 + n] * LOG2E);
        A2[n] = -ea * LOG2E;
        iv[n] = -1.0f / ea;
        h[n] = 0.f;
    }
    const int base = c * CLh;
    float cu[8], cx[8], nu[8], nx[8];
#pragma unroll
    for (int j = 0; j < 8; ++j) {
        int p = dir ? (CLh - 1 - j) : j;
        cu[j] = dt[(size_t)(base + p) * 256 + e];
        cx[j] = xc[(size_t)(base + p) * 256 + e];
    }
    __syncthreads();
    float sdt = 0.f;
#pragma unroll
    for (int g = 0; g < CLh / 8; ++g) {
        if (g + 1 < CLh / 8) {
#pragma unroll
            for (int j = 0; j < 8; ++j) {
                int s = (g + 1) * 8 + j;
                int p = dir ? (CLh - 1 - s) : s;
                nu[j] = dt[(size_t)(base + p) * 256 + e];
                nx[j] = xc[(size_t)(base + p) * 256 + e];
            }
        }
#pragma unroll
        for (int j = 0; j < 8; ++j) {
            int s = g * 8 + j;
            int p = dir ? (CLh - 1 - s) : s;
            float u = cu[j], xv = cx[j];
            union { float4 v[4]; float f[16]; } bb;
            const float4* bp = (const float4*)&bms[p][0];
            bb.v[0] = bp[0]; bb.v[1] = bp[1]; bb.v[2] = bp[2]; bb.v[3] = bp[3];
#pragma unroll
            for (int n = 0; n < 16; ++n) {
                float a = nexp2(A2[n] * u);
                float w = xv * bb.f[n] * iv[n];
                h[n] = a * (h[n] + w) - w;
            }
            sdt += u;
        }
#pragma unroll
        for (int j = 0; j < 8; ++j) { cu[j] = nu[j]; cx[j] = nx[j]; }
    }
    const size_t hofs = (size_t)(dir * NCh + c) * 4096 + e * 16;
#pragma unroll
    for (int j = 0; j < 4; ++j)
        *(float4*)&Hb[hofs + 4 * j] = make_float4(h[4 * j], h[4 * j + 1], h[4 * j + 2], h[4 * j + 3]);
    if (dir == 0) sdtb[c * 256 + e] = sdt;
}

// chunk-level scan: Hpre[c] <- prefix state entering chunk c
__global__ __launch_bounds__(64) void combine_k(const float* __restrict__ Hb, float* __restrict__ Hpre,
                                                const float* __restrict__ sdtb, const float* __restrict__ Alog) {
    int id = blockIdx.x * 64 + threadIdx.x;   // < 8192
    int dir = id >> 12, en = id & 4095, e = en >> 4;
    float A2 = -nexp2(Alog[en] * LOG2E) * LOG2E;
    float hi = 0.f;
    for (int g = 0; g < NCh / 8; ++g) {
        float Pv[8], qv[8];
#pragma unroll
        for (int j = 0; j < 8; ++j) {
            int c = dir ? (NCh - 1 - (g * 8 + j)) : (g * 8 + j);
            Pv[j] = sdtb[c * 256 + e];
            qv[j] = Hb[(size_t)(dir * NCh + c) * 4096 + en];
        }
#pragma unroll
        for (int j = 0; j < 8; ++j) {
            int c = dir ? (NCh - 1 - (g * 8 + j)) : (g * 8 + j);
            float P = nexp2(A2 * Pv[j]);
            Hpre[(size_t)(dir * NCh + c) * 4096 + en] = hi;
            hi = P * hi + qv[j];
        }
    }
}

// ---------------------------------------------------------------------------
// scan phase 1 + gate. Templated direction keeps yreg in VGPRs (no scratch).
template <int DIR>
static __device__ __forceinline__ void scan_dir(const float* __restrict__ dt, const float* __restrict__ xc,
                                                int base, int e,
                                                const float (*bms)[16], const float (*cms)[16],
                                                const float* A2, const float* iv,
                                                float* h, float* yreg) {
    float cu[8], cx[8], nu[8], nx[8];
#pragma unroll
    for (int j = 0; j < 8; ++j) {
        const int p = DIR ? (CLh - 1 - j) : j;
        cu[j] = dt[(size_t)(base + p) * 256 + e];
        cx[j] = xc[(size_t)(base + p) * 256 + e];
    }
#pragma unroll
    for (int g = 0; g < CLh / 8; ++g) {
        if (g + 1 < CLh / 8) {
#pragma unroll
            for (int j = 0; j < 8; ++j) {
                const int s = (g + 1) * 8 + j;
                const int p = DIR ? (CLh - 1 - s) : s;
                nu[j] = dt[(size_t)(base + p) * 256 + e];
                nx[j] = xc[(size_t)(base + p) * 256 + e];
            }
        }
#pragma unroll
        for (int j = 0; j < 8; ++j) {
            const int s = g * 8 + j;
            const int p = DIR ? (CLh - 1 - s) : s;
            float u = cu[j], xv = cx[j];
            union { float4 v[4]; float f[16]; } bb, cc;
            const float4* bp = (const float4*)&bms[p][0];
            bb.v[0] = bp[0]; bb.v[1] = bp[1]; bb.v[2] = bp[2]; bb.v[3] = bp[3];
            const float4* cp = (const float4*)&cms[p][0];
            cc.v[0] = cp[0]; cc.v[1] = cp[1]; cc.v[2] = cp[2]; cc.v[3] = cp[3];
            float y = 0.f;
#pragma unroll
            for (int n = 0; n < 16; ++n) {
                float a = nexp2(A2[n] * u);
                float w = xv * bb.f[n] * iv[n];
                h[n] = a * (h[n] + w) - w;
                y += h[n] * cc.f[n];
            }
            yreg[p] = y;
        }
#pragma unroll
        for (int j = 0; j < 8; ++j) { cu[j] = nu[j]; cx[j] = nx[j]; }
    }
}

__global__ __launch_bounds__(512) void scan1g_k(const float* __restrict__ dt, const float* __restrict__ xc,
                                                const float* __restrict__ Bm, const float* __restrict__ Cm,
                                                const float* __restrict__ Alog, const float* __restrict__ Hpre,
                                                const float* __restrict__ sz, const float* __restrict__ Dp,
                                                ushort* __restrict__ AHo, ushort* __restrict__ ALo) {
    const int c = blockIdx.x;
    const int tid = threadIdx.x;
    const int dir = tid >> 8;
    const int e = tid & 255;
    __shared__ float bms[CLh][16];
    __shared__ float cms[CLh][16];
    __shared__ float ysum[CLh][256];
    for (int idx = tid; idx < CLh * 16; idx += 512) {
        bms[idx >> 4][idx & 15] = Bm[c * (CLh * 16) + idx];
        cms[idx >> 4][idx & 15] = Cm[c * (CLh * 16) + idx];
    }
    float A2[16], iv[16], h[16];
#pragma unroll
    for (int n = 0; n < 16; ++n) {
        float ea = nexp2(Alog[e * 16 + n] * LOG2E);
        A2[n] = -ea * LOG2E;
        iv[n] = -1.0f / ea;
    }
    const size_t hofs = (size_t)(dir * NCh + c) * 4096 + e * 16;
#pragma unroll
    for (int j = 0; j < 4; ++j) {
        float4 hv = *(const float4*)&Hpre[hofs + 4 * j];
        h[4 * j] = hv.x; h[4 * j + 1] = hv.y; h[4 * j + 2] = hv.z; h[4 * j + 3] = hv.w;
    }
    const int base = c * CLh;
    float yreg[CLh];
    __syncthreads();
    if (dir == 0) {
        scan_dir<0>(dt, xc, base, e, bms, cms, A2, iv, h, yreg);
    } else {
        scan_dir<1>(dt, xc, base, e, bms, cms, A2, iv, h, yreg);
    }
    __syncthreads();
    if (dir == 0) {
#pragma unroll
        for (int l = 0; l < CLh; ++l) ysum[l][e] = yreg[l];
    }
    __syncthreads();
    if (dir == 1) {
        float dpv = Dp[e];
#pragma unroll
        for (int l = 0; l < CLh; ++l) {
            size_t gl = (size_t)(base + l) * 256 + e;
            float a = (ysum[l][e] + yreg[l] + dpv * xc[gl]) * sz[gl];
            ushort hh, ll; f2hl(a, &hh, &ll);
            AHo[gl] = hh; ALo[gl] = ll;
        }
    }
}

// ---------------------------------------------------------------------------
// Wout GEMM: A pre-gated bf16 hi/lo; 32x64 tiles, grid (256,2).
__global__ __launch_bounds__(256) void wout_k(const ushort* __restrict__ AH, const ushort* __restrict__ AL,
                                              const ushort* __restrict__ wH, const ushort* __restrict__ wL,
                                              const float* __restrict__ bout, const float* __restrict__ h_,
                                              ushort* __restrict__ hfH, ushort* __restrict__ hfL) {
    __shared__ ushort AsH[32][72], AsL[32][72];
    __shared__ ushort BsH[64][72], BsL[64][72];
    const int tid = threadIdx.x;
    const int lane = tid & 63, wave = tid >> 6;
    const int wm = wave & 1, wn = wave >> 1;
    const int ln = lane & 15, q = lane >> 4;
    const int mb = blockIdx.x * 32, nb = blockIdx.y * 64;

    f32x4 acc[2];
    acc[0] = (f32x4){0.f, 0.f, 0.f, 0.f};
    acc[1] = (f32x4){0.f, 0.f, 0.f, 0.f};

    for (int kc = 0; kc < 256; kc += 64) {
        __syncthreads();
        for (int u = tid; u < 256; u += 256) {
            int r = u >> 3, g = u & 7;
            size_t go = (size_t)(mb + r) * 256 + kc + g * 8;
            *(uint4*)&AsH[r][g * 8] = *(const uint4*)&AH[go];
            *(uint4*)&AsL[r][g * 8] = *(const uint4*)&AL[go];
        }
        for (int u = tid; u < 512; u += 256) {
            int n = u >> 3, g = u & 7;
            size_t go = (size_t)(W_WOUT) + (size_t)(nb + n) * 256 + kc + g * 8;
            *(uint4*)&BsH[n][g * 8] = *(const uint4*)&wH[go];
            *(uint4*)&BsL[n][g * 8] = *(const uint4*)&wL[go];
        }
        __syncthreads();
#pragma unroll
        for (int ks_ = 0; ks_ < 64; ks_ += 32) {
            const int kk = ks_ + q * 8;
            bf16x8 ah = *(const bf16x8*)&AsH[wm * 16 + ln][kk];
            bf16x8 al = *(const bf16x8*)&AsL[wm * 16 + ln][kk];
#pragma unroll
            for (int cb = 0; cb < 2; ++cb) {
                bf16x8 bh = *(const bf16x8*)&BsH[wn * 32 + cb * 16 + ln][kk];
                bf16x8 bl = *(const bf16x8*)&BsL[wn * 32 + cb * 16 + ln][kk];
                acc[cb] = __builtin_amdgcn_mfma_f32_16x16x32_bf16(ah, bh, acc[cb], 0, 0, 0);
                acc[cb] = __builtin_amdgcn_mfma_f32_16x16x32_bf16(ah, bl, acc[cb], 0, 0, 0);
                acc[cb] = __builtin_amdgcn_mfma_f32_16x16x32_bf16(al, bh, acc[cb], 0, 0, 0);
            }
        }
    }
#pragma unroll
    for (int cb = 0; cb < 2; ++cb)
#pragma unroll
        for (int r = 0; r < 4; ++r) {
            int l = mb + wm * 16 + q * 4 + r;
            int col = nb + wn * 32 + cb * 16 + ln;
            float v = acc[cb][r] + bout[col] + h_[(size_t)l * 128 + col];
            ushort hh, ll; f2hl(v, &hh, &ll);
            hfH[(size_t)l * 128 + col] = hh;
            hfL[(size_t)l * 128 + col] = ll;
        }
}

// unembed GEMM: 32x64 tiles, grid (256,2); out = hf @ pu^T + pu_b + ks (scattered)
__global__ __launch_bounds__(256) void unembed_k(const ushort* __restrict__ Ah, const ushort* __restrict__ Al,
                                                 const ushort* __restrict__ wH, const ushort* __restrict__ wL,
                                                 const float* __restrict__ pu_b, const float* __restrict__ ks,
                                                 float* __restrict__ out) {
    __shared__ ushort AsH[32][72], AsL[32][72];
    __shared__ ushort BsH[64][72], BsL[64][72];
    const int tid = threadIdx.x;
    const int lane = tid & 63, wave = tid >> 6;
    const int wm = wave & 1, wn = wave >> 1;
    const int ln = lane & 15, q = lane >> 4;
    const int mb = blockIdx.x * 32, nb = blockIdx.y * 64;

    f32x4 acc[2];
    acc[0] = (f32x4){0.f, 0.f, 0.f, 0.f};
    acc[1] = (f32x4){0.f, 0.f, 0.f, 0.f};

    for (int kc = 0; kc < 128; kc += 64) {
        __syncthreads();
        for (int u = tid; u < 256; u += 256) {
            int r = u >> 3, g = u & 7;
            size_t go = (size_t)(mb + r) * 128 + kc + g * 8;
            *(uint4*)&AsH[r][g * 8] = *(const uint4*)&Ah[go];
            *(uint4*)&AsL[r][g * 8] = *(const uint4*)&Al[go];
        }
        for (int u = tid; u < 512; u += 256) {
            int n = u >> 3, g = u & 7;
            size_t go = (size_t)(W_PU) + (size_t)(nb + n) * 128 + kc + g * 8;
            *(uint4*)&BsH[n][g * 8] = *(const uint4*)&wH[go];
            *(uint4*)&BsL[n][g * 8] = *(const uint4*)&wL[go];
        }
        __syncthreads();
#pragma unroll
        for (int ks_ = 0; ks_ < 64; ks_ += 32) {
            const int kk = ks_ + q * 8;
            bf16x8 ah = *(const bf16x8*)&AsH[wm * 16 + ln][kk];
            bf16x8 al = *(const bf16x8*)&AsL[wm * 16 + ln][kk];
#pragma unroll
            for (int cb = 0; cb < 2; ++cb) {
                bf16x8 bh = *(const bf16x8*)&BsH[wn * 32 + cb * 16 + ln][kk];
                bf16x8 bl = *(const bf16x8*)&BsL[wn * 32 + cb * 16 + ln][kk];
                acc[cb] = __builtin_amdgcn_mfma_f32_16x16x32_bf16(ah, bh, acc[cb], 0, 0, 0);
                acc[cb] = __builtin_amdgcn_mfma_f32_16x16x32_bf16(ah, bl, acc[cb], 0, 0, 0);
                acc[cb] = __builtin_amdgcn_mfma_f32_16x16x32_bf16(al, bh, acc[cb], 0, 0, 0);
            }
        }
    }
#pragma unroll
    for (int cb = 0; cb < 2; ++cb)
#pragma unroll
        for (int r = 0; r < 4; ++r) {
            int l = mb + wm * 16 + q * 4 + r;
            int col = nb + wn * 32 + cb * 16 + ln;
            int xg = l >> 8, yg = (l >> 3) & 31, zg = l & 7;
            int c = col >> 3, ijk = col & 7;
            int i2 = (ijk >> 2) & 1, j2 = (ijk >> 1) & 1, k2 = ijk & 1;
            size_t idx = (size_t)((c * 64 + 2 * xg + i2) * 64 + (2 * yg + j2)) * 16 + 2 * zg + k2;
            out[idx] = acc[cb][r] + pu_b[c] + ks[idx];
        }
}

// ---------------------------------------------------------------------------
extern "C" void kernel_launch(void* const* d_in, const int* in_sizes, int n_in,
                              void* d_out, int out_size, void* d_ws, size_t ws_size,
                              hipStream_t stream) {
    const float* ks    = (const float*)d_in[0];
    const float* mask  = (const float*)d_in[1];
    const float* pe_w  = (const float*)d_in[2];
    const float* pe_b  = (const float*)d_in[3];
    const float* pu_w  = (const float*)d_in[4];
    const float* pu_b  = (const float*)d_in[5];
    const float* ln_g  = (const float*)d_in[6];
    const float* ln_b  = (const float*)d_in[7];
    const float* fn_g  = (const float*)d_in[8];
    const float* fn_b  = (const float*)d_in[9];
    const float* cond_band = (const float*)d_in[10];
    const float* cond_rad  = (const float*)d_in[11];
    const float* cond_mask = (const float*)d_in[12];
    const float* Win   = (const float*)d_in[13];
    const float* bin_  = (const float*)d_in[14];
    const float* convw = (const float*)d_in[15];
    const float* convb = (const float*)d_in[16];
    const float* Wx    = (const float*)d_in[17];
    const float* Wdt   = (const float*)d_in[18];
    const float* bdt   = (const float*)d_in[19];
    const float* Alog  = (const float*)d_in[20];
    const float* Dp    = (const float*)d_in[21];
    const float* Wout  = (const float*)d_in[22];
    const float* bout  = (const float*)d_in[23];
    const float* edt   = (const float*)d_in[24];
    const float* eB    = (const float*)d_in[25];
    const float* eC    = (const float*)d_in[26];
    const float* wr    = (const float*)d_in[27];
    const float* wm    = (const float*)d_in[28];
    float* out = (float*)d_out;

    char* base = (char*)d_ws;
    size_t o = 0;
    auto alloc = [&](size_t bytes) { char* p = base + o; o += (bytes + 255) & ~(size_t)255; return p; };
    float*  mbuf = (float*)alloc(32768);
    ushort* wH   = (ushort*)alloc(W_TOT * 2);
    ushort* wL   = (ushort*)alloc(W_TOT * 2);
    float*  h_   = (float*)alloc(4194304);
    ushort* hnH  = (ushort*)alloc(2097152);
    ushort* hnL  = (ushort*)alloc(2097152);
    float*  xp   = (float*)alloc(8388608);
    float*  sz   = (float*)alloc(8388608);
    float*  xc   = (float*)alloc(8388608);
    float*  dt   = (float*)alloc(8388608);
    float*  Bm   = (float*)alloc(524288);
    float*  Cm   = (float*)alloc(524288);
    float*  Hb   = (float*)alloc(8388608);
    float*  Hpre = (float*)alloc(8388608);
    float*  sdtb = (float*)alloc(262144);
    ushort* AHo  = (ushort*)alloc(4194304);
    ushort* ALo  = (ushort*)alloc(4194304);
    ushort* hfH  = (ushort*)alloc(2097152);
    ushort* hfL  = (ushort*)alloc(2097152);

    prep_k<<<864, 256, 0, stream>>>(pe_w, Win, Wx, Wdt, Wout, pu_w, mask, wH, wL, mbuf);
    embed_ln_k<<<512, 256, 0, stream>>>(ks, wH, wL, pe_b, cond_band, cond_rad, cond_mask, mbuf,
                                        ln_g, ln_b, fn_g, fn_b, h_, hnH, hnL);
    win_k<<<dim3(128, 8), 256, 0, stream>>>(hnH, hnL, wH, wL, bin_, xp, sz);
    proj_k<<<256, 512, 0, stream>>>(xp, convw, convb, wH, wL, bdt, mbuf, edt, eB, eC, wr, wm,
                                    xc, dt, Bm, Cm);
    scan0_k<<<dim3(NCh, 2), 256, 0, stream>>>(dt, xc, Bm, Alog, Hb, sdtb);
    combine_k<<<128, 64, 0, stream>>>(Hb, Hpre, sdtb, Alog);
    scan1g_k<<<NCh, 512, 0, stream>>>(dt, xc, Bm, Cm, Alog, Hpre, sz, Dp, AHo, ALo);
    wout_k<<<dim3(256, 2), 256, 0, stream>>>(AHo, ALo, wH, wL, bout, h_, hfH, hfL);
    unembed_k<<<dim3(256, 2), 256, 0, stream>>>(hfH, hfL, wH, wL, pu_b, ks, out);
}